// Round 15
// baseline (70.297 us; speedup 1.0000x reference)
//
#include <hip/hip_runtime.h>
#include <hip/hip_bf16.h>

#define T_ 64
#define S_ 64
#define B_ 128
#define E_ 64
#define H_ 4

typedef float f32x4 __attribute__((ext_vector_type(4)));
typedef short bf16x8 __attribute__((ext_vector_type(8)));

static __device__ __forceinline__ short f2b(float f) {
    union { __hip_bfloat16 h; short s; } u;
    u.h = __float2bfloat16(f);
    return u.s;
}

// ---------------------------------------------------------------------------
// K1: qkv projection (R9, unchanged). qkv layout: [3][T][B][E].
// Block 256 preps relW bf16 fragment-linear (frags 0..15) + 4 shifted-identity
// frags (16..19) into wBf; seg==1 also emits kpb[j] = (k + rel_bias_b) bf16
// A-fragment pages so k_logits needs no scalar k loads.
// ---------------------------------------------------------------------------
__global__ __launch_bounds__(256) void k_qkv(
    const float* __restrict__ qin, const float* __restrict__ kin,
    const float* __restrict__ vin, const float* __restrict__ W,
    const float* __restrict__ bias, float* __restrict__ qkv,
    const float* __restrict__ relW, const float* __restrict__ relBias,
    ushort* __restrict__ wBf, unsigned int* __restrict__ kpbW)
{
    const int tid = threadIdx.x;

    if (blockIdx.x == 256) {
        #pragma unroll
        for (int li = 0; li < 8; ++li) {
            int f4 = li * 256 + tid;             // 0..2047 = o*16 + e4
            int o = f4 >> 4, e4 = f4 & 15;
            float4 wv = reinterpret_cast<const float4*>(relW)[f4];
            ushort4 bv;
            bv.x = (ushort)f2b(wv.x); bv.y = (ushort)f2b(wv.y);
            bv.z = (ushort)f2b(wv.z); bv.w = (ushort)f2b(wv.w);
            int ot = o >> 4, cc = o & 15;
            int ks = e4 >> 3, rqb = (e4 & 7) >> 1, half = e4 & 1;
            int dest = (ot * 2 + ks) * 512 + (rqb * 16 + cc) * 8 + half * 4;
            *reinterpret_cast<ushort4*>(wBf + dest) = bv;
        }
        #pragma unroll
        for (int li = 0; li < 8; ++li) {
            int t = li * 256 + tid;              // 0..2047
            int ot = t >> 9, lane = (t >> 3) & 63, e = t & 7;
            int cI = lane & 15, rqI = lane >> 4;
            wBf[8192 + t] =
                (rqI * 8 + e == (ot & 1) * 16 + cI) ? (ushort)0x3F80 : (ushort)0;
        }
        return;
    }

    __shared__ float xs[3][32 * 68];
    __shared__ float WTs[64 * 68];
    const int row0 = blockIdx.x * 32;

    #pragma unroll
    for (int l = 0; l < 6; ++l) {
        int f4 = l * 256 + tid;
        int src = f4 >> 9, rem = f4 & 511;
        int r = rem >> 4, e0 = (rem & 15) << 2;
        const float* xin = (src == 0) ? qin : (src == 1 ? kin : vin);
        float4 xv = reinterpret_cast<const float4*>(xin)[(size_t)(row0 + r) * 16 + (e0 >> 2)];
        float* dst = &xs[src][r * 68];
        dst[e0] = xv.x; dst[e0 + 1] = xv.y; dst[e0 + 2] = xv.z; dst[e0 + 3] = xv.w;
    }

    const int rq = tid >> 5, og = tid & 31;
    const int r0 = rq * 4, op0 = og * 2;

    for (int seg = 0; seg < 3; ++seg) {
        __syncthreads();
        #pragma unroll
        for (int l = 0; l < 4; ++l) {
            int f4 = l * 256 + tid;
            int o = f4 >> 4, e0 = (f4 & 15) << 2;
            float4 wv = reinterpret_cast<const float4*>(W)[(size_t)(seg * 64 + o) * 16 + (e0 >> 2)];
            WTs[(e0 + 0) * 68 + o] = wv.x; WTs[(e0 + 1) * 68 + o] = wv.y;
            WTs[(e0 + 2) * 68 + o] = wv.z; WTs[(e0 + 3) * 68 + o] = wv.w;
        }
        __syncthreads();

        float acc[4][2];
        #pragma unroll
        for (int rr = 0; rr < 4; ++rr) {
            acc[rr][0] = bias[seg * 64 + op0];
            acc[rr][1] = bias[seg * 64 + op0 + 1];
        }
        const float* xsrc = xs[seg];
        #pragma unroll 4
        for (int e = 0; e < 64; ++e) {
            float w0 = WTs[e * 68 + op0];
            float w1 = WTs[e * 68 + op0 + 1];
            #pragma unroll
            for (int rr = 0; rr < 4; ++rr) {
                float xv = xsrc[(r0 + rr) * 68 + e];
                acc[rr][0] += xv * w0;
                acc[rr][1] += xv * w1;
            }
        }
        #pragma unroll
        for (int rr = 0; rr < 4; ++rr) {
            float2 ov = make_float2(acc[rr][0], acc[rr][1]);
            reinterpret_cast<float2*>(
                &qkv[((size_t)seg * T_ * B_ + row0 + r0 + rr) * E_ + op0])[0] = ov;
        }
        if (seg == 1) {
            #pragma unroll
            for (int rr = 0; rr < 4; ++rr) {
                int row = row0 + r0 + rr;         // = j*128 + b
                int jj = row >> 7, b = row & 127;
                float kb0 = acc[rr][0] + relBias[64 + op0];
                float kb1 = acc[rr][1] + relBias[64 + op0 + 1];
                unsigned int u = (unsigned int)(ushort)f2b(kb0) |
                                 ((unsigned int)(ushort)f2b(kb1) << 16);
                int off = jj * 8192 + (op0 >> 5) * 4096 + (b >> 4) * 512 +
                          ((b & 15) + ((op0 & 31) >> 3) * 16) * 8 + (op0 & 7);
                kpbW[off >> 1] = u;
            }
        }
    }
}

// ---------------------------------------------------------------------------
// K2a: fused relation-projection + logits (MONOTONE distance-3 pipeline).
// R14 post-mortem: kf(T) was issued at body T, YOUNGER than the in-flight
// A-prefetches, so the I-step MFMA's vmcnt wait on kf(T) drained them all ->
// effective depth 1 (same as R9, hence neutral). Fix: kf prefetched at
// DISTANCE 2 into 3 rotating named pairs, issued BEFORE LOADA(T+3); per-body
// order = cvt(X(T)) [drains only <= LOADA(T)] -> kf(T+2) issue ->
// LOADA(T+3) issue -> MFMA [kf(T) wait drains only <= body T-2's issue] ->
// epilogue. Waitcnt chain is now monotone: LOADA(T+1..T+3) + kf(T+1..T+2)
// stay in flight through MFMA+epilogue ~= 12.5 KB/wave x 16 waves ~=
// 200 KB/CU -> the 6 TB/s regime R13's k_prefetch proved (128 KB -> 6.4).
// (512,2): 16 waves/CU, 128-VGPR cap, ~108 used.
// ---------------------------------------------------------------------------
__global__ __launch_bounds__(512, 2) void k_logits_mfma(
    const float* __restrict__ rel, const ushort* __restrict__ wBf,
    const ushort* __restrict__ kpbF, const float* __restrict__ relBias,
    const float* __restrict__ qkv, float* __restrict__ logits)
{
    __shared__ char  Bs[20480];        // 20 B-frags (16 W + 4 I), 1 KB each
    __shared__ float llds[8][64][9];   // per-lane logit buffer (stride 9)

    const int tid = threadIdx.x;
    const int w = tid >> 6, l = tid & 63;
    const int c = l & 15, rq = l >> 4;
    const int i = blockIdx.x >> 3;
    const int jb = (blockIdx.x & 7) * 8;

    // stage Bs (20 KB linear copy)
    #pragma unroll
    for (int li = 0; li < 3; ++li) {
        int idx = li * 512 + tid;
        if (idx < 1280)
            reinterpret_cast<float4*>(Bs)[idx] =
                reinterpret_cast<const float4*>(wBf)[idx];
    }

    // hoist qpre = q + ba (j-invariant)
    float qpre[4][4];
    {
        const float* qrow = qkv + (size_t)i * (B_ * E_);
        #pragma unroll
        for (int h = 0; h < 4; ++h) {
            float ba = relBias[h * 16 + c];
            #pragma unroll
            for (int r = 0; r < 4; ++r)
                qpre[h][r] = qrow[(w * 16 + rq * 4 + r) * E_ + h * 16 + c] + ba;
        }
    }
    __syncthreads();

    const int arow = (w * 16 + c) * E_ + rq * 8;
    const int kfo  = w * 512 + l * 8;

#define LOADA(jj, X0, X1, X2, X3)                                              \
    {                                                                          \
        const float* ab = rel + ((size_t)(jj) * S_ + i) * (size_t)(B_ * E_) + arow; \
        X0 = *(const float4*)(ab);                                             \
        X1 = *(const float4*)(ab + 4);                                         \
        X2 = *(const float4*)(ab + 32);                                        \
        X3 = *(const float4*)(ab + 36);                                        \
    }

#define LOADKF(jj, K0, K1)                                                     \
    {                                                                          \
        K0 = *(const bf16x8*)(kpbF + (size_t)(jj) * 8192 + kfo);               \
        K1 = *(const bf16x8*)(kpbF + (size_t)(jj) * 8192 + 4096 + kfo);        \
    }

// One j-step, T literal. KC = kf pair for j=T (loaded at body T-2);
// KN = kf pair to refill with j=T+2. Order per the monotone-waitcnt design.
#define BODY(T, X0, X1, X2, X3, KC0, KC1, KN0, KN1)                            \
    {                                                                          \
        bf16x8 af0, af1;                                                       \
        {                                                                      \
            bf16x8 a;                                                          \
            a[0] = f2b(X0.x); a[1] = f2b(X0.y); a[2] = f2b(X0.z); a[3] = f2b(X0.w); \
            a[4] = f2b(X1.x); a[5] = f2b(X1.y); a[6] = f2b(X1.z); a[7] = f2b(X1.w); \
            af0 = a;                                                           \
            a[0] = f2b(X2.x); a[1] = f2b(X2.y); a[2] = f2b(X2.z); a[3] = f2b(X2.w); \
            a[4] = f2b(X3.x); a[5] = f2b(X3.y); a[6] = f2b(X3.z); a[7] = f2b(X3.w); \
            af1 = a;                                                           \
        }                                                                      \
        if ((T) + 2 < 8) { LOADKF(jb + (T) + 2, KN0, KN1) }                    \
        if ((T) + 3 < 8) { LOADA(jb + (T) + 3, X0, X1, X2, X3) }               \
        int bs0 = 0;                                                           \
        asm volatile("" : "+v"(bs0));                                          \
        const char* bsp = Bs + bs0;                                            \
        f32x4 acc[8];                                                          \
        _Pragma("unroll")                                                      \
        for (int ot = 0; ot < 8; ++ot) acc[ot] = (f32x4){0.f, 0.f, 0.f, 0.f}; \
        _Pragma("unroll")                                                      \
        for (int ot = 0; ot < 4; ++ot) {   /* pa = W_a . rel */                \
            acc[ot] = __builtin_amdgcn_mfma_f32_16x16x32_bf16(                 \
                af0, *(const bf16x8*)(bsp + (ot * 2 + 0) * 1024 + l * 16), acc[ot], 0, 0, 0); \
            acc[ot] = __builtin_amdgcn_mfma_f32_16x16x32_bf16(                 \
                af1, *(const bf16x8*)(bsp + (ot * 2 + 1) * 1024 + l * 16), acc[ot], 0, 0, 0); \
        }                                                                      \
        _Pragma("unroll")                                                      \
        for (int ot = 0; ot < 4; ++ot) {   /* pb = W_b . rel + (k+bb) */       \
            acc[4 + ot] = __builtin_amdgcn_mfma_f32_16x16x32_bf16(             \
                af0, *(const bf16x8*)(bsp + (8 + ot * 2 + 0) * 1024 + l * 16), acc[4 + ot], 0, 0, 0); \
            acc[4 + ot] = __builtin_amdgcn_mfma_f32_16x16x32_bf16(             \
                af1, *(const bf16x8*)(bsp + (8 + ot * 2 + 1) * 1024 + l * 16), acc[4 + ot], 0, 0, 0); \
            acc[4 + ot] = __builtin_amdgcn_mfma_f32_16x16x32_bf16(             \
                (ot < 2 ? KC0 : KC1),                                          \
                *(const bf16x8*)(bsp + (16 + ot) * 1024 + l * 16), acc[4 + ot], 0, 0, 0); \
        }                                                                      \
        float v[16];                                                           \
        _Pragma("unroll")                                                      \
        for (int h = 0; h < 4; ++h)                                            \
            _Pragma("unroll")                                                  \
            for (int r = 0; r < 4; ++r)                                        \
                v[h * 4 + r] = (qpre[h][r] + acc[h][r]) * acc[4 + h][r];       \
        _Pragma("unroll")                                                      \
        for (int k = 0; k < 8; ++k) {                                          \
            float x = (c & 1) ? v[2 * k + 1] : v[2 * k];                       \
            float y = (c & 1) ? v[2 * k] : v[2 * k + 1];                       \
            v[k] = x + __shfl_xor(y, 1);                                       \
        }                                                                      \
        _Pragma("unroll")                                                      \
        for (int k = 0; k < 4; ++k) {                                          \
            float x = (c & 2) ? v[2 * k + 1] : v[2 * k];                       \
            float y = (c & 2) ? v[2 * k] : v[2 * k + 1];                       \
            v[k] = x + __shfl_xor(y, 2);                                       \
        }                                                                      \
        _Pragma("unroll")                                                      \
        for (int k = 0; k < 2; ++k) {                                          \
            float x = (c & 4) ? v[2 * k + 1] : v[2 * k];                       \
            float y = (c & 4) ? v[2 * k] : v[2 * k + 1];                       \
            v[k] = x + __shfl_xor(y, 4);                                       \
        }                                                                      \
        {                                                                      \
            float x = (c & 8) ? v[1] : v[0];                                   \
            float y = (c & 8) ? v[0] : v[1];                                   \
            llds[w][l][(T)] = (x + __shfl_xor(y, 8)) * 0.0625f;                \
        }                                                                      \
    }

    float4 xA0, xA1, xA2, xA3, xB0, xB1, xB2, xB3, xC0, xC1, xC2, xC3;
    bf16x8 kfA0, kfA1, kfB0, kfB1, kfC0, kfC1;
    LOADA(jb + 0, xA0, xA1, xA2, xA3)
    LOADKF(jb + 0, kfA0, kfA1)
    LOADA(jb + 1, xB0, xB1, xB2, xB3)
    LOADKF(jb + 1, kfB0, kfB1)
    LOADA(jb + 2, xC0, xC1, xC2, xC3)

    BODY(0, xA0, xA1, xA2, xA3, kfA0, kfA1, kfC0, kfC1)   // fills kfC = j2
    BODY(1, xB0, xB1, xB2, xB3, kfB0, kfB1, kfA0, kfA1)   // fills kfA = j3
    BODY(2, xC0, xC1, xC2, xC3, kfC0, kfC1, kfB0, kfB1)   // fills kfB = j4
    BODY(3, xA0, xA1, xA2, xA3, kfA0, kfA1, kfC0, kfC1)   // fills kfC = j5
    BODY(4, xB0, xB1, xB2, xB3, kfB0, kfB1, kfA0, kfA1)   // fills kfA = j6
    BODY(5, xC0, xC1, xC2, xC3, kfC0, kfC1, kfB0, kfB1)   // fills kfB = j7
    BODY(6, xA0, xA1, xA2, xA3, kfA0, kfA1, kfC0, kfC1)   // no fill (T+2>=8)
    BODY(7, xB0, xB1, xB2, xB3, kfB0, kfB1, kfC0, kfC1)   // no fill
#undef BODY
#undef LOADKF
#undef LOADA

    // flush: lane (w,rq,c) owns logits[i][b=w*16+rq*4+(c&3)][h=c>>2][jb..jb+7]
    {
        float f[8];
        #pragma unroll
        for (int t2 = 0; t2 < 8; ++t2) f[t2] = llds[w][l][t2];
        const int hh = c >> 2, rr = c & 3;
        const int b = w * 16 + rq * 4 + rr;
        float* dst = &logits[(((size_t)i * B_ + b) * H_ + hh) * S_ + jb];
        *reinterpret_cast<float4*>(dst) = make_float4(f[0], f[1], f[2], f[3]);
        *reinterpret_cast<float4*>(dst + 4) = make_float4(f[4], f[5], f[6], f[7]);
    }
}

// ---------------------------------------------------------------------------
// K2b: softmax over j + PV + out-projection (R9, unchanged). logits [i][b][h][j].
// ---------------------------------------------------------------------------
__global__ __launch_bounds__(256) void k_attn(
    const float* __restrict__ logits, const float* __restrict__ qkv,
    const float* __restrict__ Wout, const float* __restrict__ bout,
    float* __restrict__ out)
{
    __shared__ float wsm[4][H_][S_];
    __shared__ float ap[4][68];
    const int tid = threadIdx.x;
    const int i = blockIdx.x >> 5;
    const int bq = blockIdx.x & 31;
    const int w = tid >> 6, l = tid & 63;
    const int b = bq * 4 + w;

    const float* lg = logits + ((size_t)i * B_ + b) * H_ * S_;
    const int h = l >> 4, sub = l & 15;
    float v0 = lg[h * S_ + sub];
    float v1 = lg[h * S_ + sub + 16];
    float v2 = lg[h * S_ + sub + 32];
    float v3 = lg[h * S_ + sub + 48];
    float m = fmaxf(fmaxf(v0, v1), fmaxf(v2, v3));
    #pragma unroll
    for (int d = 1; d < 16; d <<= 1) m = fmaxf(m, __shfl_xor(m, d));
    float e0 = expf(v0 - m), e1 = expf(v1 - m), e2 = expf(v2 - m), e3 = expf(v3 - m);
    float ss = e0 + e1 + e2 + e3;
    #pragma unroll
    for (int d = 1; d < 16; d <<= 1) ss += __shfl_xor(ss, d);
    float inv = 1.0f / ss;
    wsm[w][h][sub] = e0 * inv;
    wsm[w][h][sub + 16] = e1 * inv;
    wsm[w][h][sub + 32] = e2 * inv;
    wsm[w][h][sub + 48] = e3 * inv;
    __syncthreads();

    const float* vbase = qkv + (size_t)2 * T_ * B_ * E_ + (size_t)b * E_;
    const float* wrow = &wsm[w][l >> 4][0];
    float acc = 0.f;
    #pragma unroll 4
    for (int j = 0; j < S_; ++j) acc += wrow[j] * vbase[(size_t)j * B_ * E_ + l];
    ap[w][l] = acc;
    __syncthreads();

    const float* wo = Wout + l * E_;
    const float* apw = ap[w];
    float oacc = bout[l];
    #pragma unroll 4
    for (int e = 0; e < E_; ++e) oacc += apw[e] * wo[e];
    out[((size_t)i * B_ + b) * E_ + l] = oacc;
}

// ---------------------------------------------------------------------------
extern "C" void kernel_launch(void* const* d_in, const int* in_sizes, int n_in,
                              void* d_out, int out_size, void* d_ws, size_t ws_size,
                              hipStream_t stream)
{
    const float* qin = (const float*)d_in[0];
    const float* kin = (const float*)d_in[1];
    const float* vin = (const float*)d_in[2];
    const float* rel = (const float*)d_in[3];
    const float* ipw = (const float*)d_in[4];
    const float* ipb = (const float*)d_in[5];
    const float* rw  = (const float*)d_in[6];
    const float* rb  = (const float*)d_in[7];
    const float* ow  = (const float*)d_in[8];
    const float* obias = (const float*)d_in[9];

    float* qkv = (float*)d_ws;                        // 3*64*128*64 fl = 6 MB
    float* logits = qkv + 3 * T_ * B_ * E_;           // [i][b][h][j]  = 8 MB
    ushort* wBf  = (ushort*)(logits + (size_t)T_ * S_ * B_ * H_); // 20 KB (+pad)
    ushort* kpbF = wBf + 16384;                       // 64 pages x 16 KB = 1 MB

    float* out = (float*)d_out;

    k_qkv<<<dim3(257), dim3(256), 0, stream>>>(qin, kin, vin, ipw, ipb, qkv,
                                               rw, rb, wBf, (unsigned int*)kpbF);
    k_logits_mfma<<<dim3(512), dim3(512), 0, stream>>>(rel, wBf, kpbF, rb, qkv, logits);
    k_attn<<<dim3(2048), dim3(256), 0, stream>>>(logits, qkv, ow, obias, out);
}

// Round 16
// 66.389 us; speedup vs baseline: 1.0589x; 1.0589x over previous
//
#include <hip/hip_runtime.h>
#include <hip/hip_bf16.h>

#define T_ 64
#define S_ 64
#define B_ 128
#define E_ 64
#define H_ 4

typedef float f32x4 __attribute__((ext_vector_type(4)));
typedef short bf16x8 __attribute__((ext_vector_type(8)));

static __device__ __forceinline__ short f2b(float f) {
    union { __hip_bfloat16 h; short s; } u;
    u.h = __float2bfloat16(f);
    return u.s;
}

// ---------------------------------------------------------------------------
// K1: qkv projection (R9, unchanged). qkv layout: [3][T][B][E].
// Block 256 preps relW bf16 fragment-linear (frags 0..15) + 4 shifted-identity
// frags (16..19) into wBf; seg==1 also emits kpb[j] = (k + rel_bias_b) bf16
// A-fragment pages so k_logits needs no scalar k loads.
// ---------------------------------------------------------------------------
__global__ __launch_bounds__(256) void k_qkv(
    const float* __restrict__ qin, const float* __restrict__ kin,
    const float* __restrict__ vin, const float* __restrict__ W,
    const float* __restrict__ bias, float* __restrict__ qkv,
    const float* __restrict__ relW, const float* __restrict__ relBias,
    ushort* __restrict__ wBf, unsigned int* __restrict__ kpbW)
{
    const int tid = threadIdx.x;

    if (blockIdx.x == 256) {
        #pragma unroll
        for (int li = 0; li < 8; ++li) {
            int f4 = li * 256 + tid;             // 0..2047 = o*16 + e4
            int o = f4 >> 4, e4 = f4 & 15;
            float4 wv = reinterpret_cast<const float4*>(relW)[f4];
            ushort4 bv;
            bv.x = (ushort)f2b(wv.x); bv.y = (ushort)f2b(wv.y);
            bv.z = (ushort)f2b(wv.z); bv.w = (ushort)f2b(wv.w);
            int ot = o >> 4, cc = o & 15;
            int ks = e4 >> 3, rqb = (e4 & 7) >> 1, half = e4 & 1;
            int dest = (ot * 2 + ks) * 512 + (rqb * 16 + cc) * 8 + half * 4;
            *reinterpret_cast<ushort4*>(wBf + dest) = bv;
        }
        #pragma unroll
        for (int li = 0; li < 8; ++li) {
            int t = li * 256 + tid;              // 0..2047
            int ot = t >> 9, lane = (t >> 3) & 63, e = t & 7;
            int cI = lane & 15, rqI = lane >> 4;
            wBf[8192 + t] =
                (rqI * 8 + e == (ot & 1) * 16 + cI) ? (ushort)0x3F80 : (ushort)0;
        }
        return;
    }

    __shared__ float xs[3][32 * 68];
    __shared__ float WTs[64 * 68];
    const int row0 = blockIdx.x * 32;

    #pragma unroll
    for (int l = 0; l < 6; ++l) {
        int f4 = l * 256 + tid;
        int src = f4 >> 9, rem = f4 & 511;
        int r = rem >> 4, e0 = (rem & 15) << 2;
        const float* xin = (src == 0) ? qin : (src == 1 ? kin : vin);
        float4 xv = reinterpret_cast<const float4*>(xin)[(size_t)(row0 + r) * 16 + (e0 >> 2)];
        float* dst = &xs[src][r * 68];
        dst[e0] = xv.x; dst[e0 + 1] = xv.y; dst[e0 + 2] = xv.z; dst[e0 + 3] = xv.w;
    }

    const int rq = tid >> 5, og = tid & 31;
    const int r0 = rq * 4, op0 = og * 2;

    for (int seg = 0; seg < 3; ++seg) {
        __syncthreads();
        #pragma unroll
        for (int l = 0; l < 4; ++l) {
            int f4 = l * 256 + tid;
            int o = f4 >> 4, e0 = (f4 & 15) << 2;
            float4 wv = reinterpret_cast<const float4*>(W)[(size_t)(seg * 64 + o) * 16 + (e0 >> 2)];
            WTs[(e0 + 0) * 68 + o] = wv.x; WTs[(e0 + 1) * 68 + o] = wv.y;
            WTs[(e0 + 2) * 68 + o] = wv.z; WTs[(e0 + 3) * 68 + o] = wv.w;
        }
        __syncthreads();

        float acc[4][2];
        #pragma unroll
        for (int rr = 0; rr < 4; ++rr) {
            acc[rr][0] = bias[seg * 64 + op0];
            acc[rr][1] = bias[seg * 64 + op0 + 1];
        }
        const float* xsrc = xs[seg];
        #pragma unroll 4
        for (int e = 0; e < 64; ++e) {
            float w0 = WTs[e * 68 + op0];
            float w1 = WTs[e * 68 + op0 + 1];
            #pragma unroll
            for (int rr = 0; rr < 4; ++rr) {
                float xv = xsrc[(r0 + rr) * 68 + e];
                acc[rr][0] += xv * w0;
                acc[rr][1] += xv * w1;
            }
        }
        #pragma unroll
        for (int rr = 0; rr < 4; ++rr) {
            float2 ov = make_float2(acc[rr][0], acc[rr][1]);
            reinterpret_cast<float2*>(
                &qkv[((size_t)seg * T_ * B_ + row0 + r0 + rr) * E_ + op0])[0] = ov;
        }
        if (seg == 1) {
            #pragma unroll
            for (int rr = 0; rr < 4; ++rr) {
                int row = row0 + r0 + rr;         // = j*128 + b
                int jj = row >> 7, b = row & 127;
                float kb0 = acc[rr][0] + relBias[64 + op0];
                float kb1 = acc[rr][1] + relBias[64 + op0 + 1];
                unsigned int u = (unsigned int)(ushort)f2b(kb0) |
                                 ((unsigned int)(ushort)f2b(kb1) << 16);
                int off = jj * 8192 + (op0 >> 5) * 4096 + (b >> 4) * 512 +
                          ((b & 15) + ((op0 & 31) >> 3) * 16) * 8 + (op0 & 7);
                kpbW[off >> 1] = u;
            }
        }
    }
}

// ---------------------------------------------------------------------------
// K2a: fused relation-projection + logits — R9 kernel BYTE-IDENTICAL except
// __launch_bounds__(512, 4): 4 wg/CU x 8 waves = 32 waves/CU (the max),
// VGPR cap 64 (R9 measured 52 -> fits, no spill). LDS 38.9 KB x 4 = 155.6 KB
// <= 160 KB. Rationale: every <=16-wave variant hit the same ~2.7 TB/s cold
// wall; the ONLY 6.4 TB/s config (k_prefetch, R13) ran 32 waves/CU. This
// tests occupancy as the governing term of the Little's-law model with one
// token changed from the proven-best 66.1us kernel.
// ---------------------------------------------------------------------------
__global__ __launch_bounds__(512, 4) void k_logits_mfma(
    const float* __restrict__ rel, const ushort* __restrict__ wBf,
    const ushort* __restrict__ kpbF, const float* __restrict__ relBias,
    const float* __restrict__ qkv, float* __restrict__ logits)
{
    __shared__ char  Bs[20480];        // 20 B-frags (16 W + 4 I), 1 KB each
    __shared__ float llds[8][64][9];   // per-lane logit buffer (stride 9)

    const int tid = threadIdx.x;
    const int w = tid >> 6, l = tid & 63;
    const int c = l & 15, rq = l >> 4;
    const int i = blockIdx.x >> 3;
    const int jb = (blockIdx.x & 7) * 8;

    // stage Bs (20 KB linear copy)
    #pragma unroll
    for (int li = 0; li < 3; ++li) {
        int idx = li * 512 + tid;
        if (idx < 1280)
            reinterpret_cast<float4*>(Bs)[idx] =
                reinterpret_cast<const float4*>(wBf)[idx];
    }

    // hoist qpre = q + ba (j-invariant)
    float qpre[4][4];
    {
        const float* qrow = qkv + (size_t)i * (B_ * E_);
        #pragma unroll
        for (int h = 0; h < 4; ++h) {
            float ba = relBias[h * 16 + c];
            #pragma unroll
            for (int r = 0; r < 4; ++r)
                qpre[h][r] = qrow[(w * 16 + rq * 4 + r) * E_ + h * 16 + c] + ba;
        }
    }
    __syncthreads();

    const int arow = (w * 16 + c) * E_ + rq * 8;
    const int kfo  = w * 512 + l * 8;

    float4 x0, x1, x2, x3;
    {
        const float* ab = rel + ((size_t)jb * S_ + i) * (size_t)(B_ * E_) + arow;
        x0 = *(const float4*)(ab);
        x1 = *(const float4*)(ab + 4);
        x2 = *(const float4*)(ab + 32);
        x3 = *(const float4*)(ab + 36);
    }

    #pragma unroll 1
    for (int t = 0; t < 8; ++t) {
        const int j = jb + t;

        // kpb A-frags for this j (bf16, no cvt needed)
        bf16x8 kf0 = *(const bf16x8*)(kpbF + (size_t)j * 8192 + kfo);
        bf16x8 kf1 = *(const bf16x8*)(kpbF + (size_t)j * 8192 + 4096 + kfo);

        // cvt this j's A (waits on x-loads issued last iteration)
        bf16x8 af0, af1;
        {
            bf16x8 a;
            a[0] = f2b(x0.x); a[1] = f2b(x0.y); a[2] = f2b(x0.z); a[3] = f2b(x0.w);
            a[4] = f2b(x1.x); a[5] = f2b(x1.y); a[6] = f2b(x1.z); a[7] = f2b(x1.w);
            af0 = a;
            a[0] = f2b(x2.x); a[1] = f2b(x2.y); a[2] = f2b(x2.z); a[3] = f2b(x2.w);
            a[4] = f2b(x3.x); a[5] = f2b(x3.y); a[6] = f2b(x3.z); a[7] = f2b(x3.w);
            af1 = a;
        }

        // prefetch next j's A (lands during MFMA + epilogue of this j)
        if (t < 7) {
            const float* ab = rel + ((size_t)(j + 1) * S_ + i) * (size_t)(B_ * E_) + arow;
            x0 = *(const float4*)(ab);
            x1 = *(const float4*)(ab + 4);
            x2 = *(const float4*)(ab + 32);
            x3 = *(const float4*)(ab + 36);
        }

        // opaque offset: stops LICM from hoisting the 20 B-frag LDS reads
        int bs0 = 0;
        asm volatile("" : "+v"(bs0));
        const char* bsp = Bs + bs0;

        f32x4 acc[8];
        #pragma unroll
        for (int ot = 0; ot < 8; ++ot) acc[ot] = (f32x4){0.f, 0.f, 0.f, 0.f};
        #pragma unroll
        for (int ot = 0; ot < 4; ++ot) {   // pa = W_a . rel
            acc[ot] = __builtin_amdgcn_mfma_f32_16x16x32_bf16(
                af0, *(const bf16x8*)(bsp + (ot * 2 + 0) * 1024 + l * 16), acc[ot], 0, 0, 0);
            acc[ot] = __builtin_amdgcn_mfma_f32_16x16x32_bf16(
                af1, *(const bf16x8*)(bsp + (ot * 2 + 1) * 1024 + l * 16), acc[ot], 0, 0, 0);
        }
        #pragma unroll
        for (int ot = 0; ot < 4; ++ot) {   // pb = W_b . rel + (k+bb) via I-step
            acc[4 + ot] = __builtin_amdgcn_mfma_f32_16x16x32_bf16(
                af0, *(const bf16x8*)(bsp + (8 + ot * 2 + 0) * 1024 + l * 16), acc[4 + ot], 0, 0, 0);
            acc[4 + ot] = __builtin_amdgcn_mfma_f32_16x16x32_bf16(
                af1, *(const bf16x8*)(bsp + (8 + ot * 2 + 1) * 1024 + l * 16), acc[4 + ot], 0, 0, 0);
            acc[4 + ot] = __builtin_amdgcn_mfma_f32_16x16x32_bf16(
                (ot < 2 ? kf0 : kf1),
                *(const bf16x8*)(bsp + (16 + ot) * 1024 + l * 16), acc[4 + ot], 0, 0, 0);
        }

        // epilogue: v[h*4+r]; butterfly reduce-scatter over c-lanes
        float v[16];
        #pragma unroll
        for (int h = 0; h < 4; ++h)
            #pragma unroll
            for (int r = 0; r < 4; ++r)
                v[h * 4 + r] = (qpre[h][r] + acc[h][r]) * acc[4 + h][r];
        #pragma unroll
        for (int k = 0; k < 8; ++k) {
            float x = (c & 1) ? v[2 * k + 1] : v[2 * k];
            float y = (c & 1) ? v[2 * k] : v[2 * k + 1];
            v[k] = x + __shfl_xor(y, 1);
        }
        #pragma unroll
        for (int k = 0; k < 4; ++k) {
            float x = (c & 2) ? v[2 * k + 1] : v[2 * k];
            float y = (c & 2) ? v[2 * k] : v[2 * k + 1];
            v[k] = x + __shfl_xor(y, 2);
        }
        #pragma unroll
        for (int k = 0; k < 2; ++k) {
            float x = (c & 4) ? v[2 * k + 1] : v[2 * k];
            float y = (c & 4) ? v[2 * k] : v[2 * k + 1];
            v[k] = x + __shfl_xor(y, 4);
        }
        {
            float x = (c & 8) ? v[1] : v[0];
            float y = (c & 8) ? v[0] : v[1];
            llds[w][l][t] = (x + __shfl_xor(y, 8)) * 0.0625f;
        }
    }

    // flush: lane (w,rq,c) owns logits[i][b=w*16+rq*4+(c&3)][h=c>>2][jb..jb+7]
    {
        float f[8];
        #pragma unroll
        for (int t2 = 0; t2 < 8; ++t2) f[t2] = llds[w][l][t2];
        const int hh = c >> 2, rr = c & 3;
        const int b = w * 16 + rq * 4 + rr;
        float* dst = &logits[(((size_t)i * B_ + b) * H_ + hh) * S_ + jb];
        *reinterpret_cast<float4*>(dst) = make_float4(f[0], f[1], f[2], f[3]);
        *reinterpret_cast<float4*>(dst + 4) = make_float4(f[4], f[5], f[6], f[7]);
    }
}

// ---------------------------------------------------------------------------
// K2b: softmax over j + PV + out-projection (R9, unchanged). logits [i][b][h][j].
// ---------------------------------------------------------------------------
__global__ __launch_bounds__(256) void k_attn(
    const float* __restrict__ logits, const float* __restrict__ qkv,
    const float* __restrict__ Wout, const float* __restrict__ bout,
    float* __restrict__ out)
{
    __shared__ float wsm[4][H_][S_];
    __shared__ float ap[4][68];
    const int tid = threadIdx.x;
    const int i = blockIdx.x >> 5;
    const int bq = blockIdx.x & 31;
    const int w = tid >> 6, l = tid & 63;
    const int b = bq * 4 + w;

    const float* lg = logits + ((size_t)i * B_ + b) * H_ * S_;
    const int h = l >> 4, sub = l & 15;
    float v0 = lg[h * S_ + sub];
    float v1 = lg[h * S_ + sub + 16];
    float v2 = lg[h * S_ + sub + 32];
    float v3 = lg[h * S_ + sub + 48];
    float m = fmaxf(fmaxf(v0, v1), fmaxf(v2, v3));
    #pragma unroll
    for (int d = 1; d < 16; d <<= 1) m = fmaxf(m, __shfl_xor(m, d));
    float e0 = expf(v0 - m), e1 = expf(v1 - m), e2 = expf(v2 - m), e3 = expf(v3 - m);
    float ss = e0 + e1 + e2 + e3;
    #pragma unroll
    for (int d = 1; d < 16; d <<= 1) ss += __shfl_xor(ss, d);
    float inv = 1.0f / ss;
    wsm[w][h][sub] = e0 * inv;
    wsm[w][h][sub + 16] = e1 * inv;
    wsm[w][h][sub + 32] = e2 * inv;
    wsm[w][h][sub + 48] = e3 * inv;
    __syncthreads();

    const float* vbase = qkv + (size_t)2 * T_ * B_ * E_ + (size_t)b * E_;
    const float* wrow = &wsm[w][l >> 4][0];
    float acc = 0.f;
    #pragma unroll 4
    for (int j = 0; j < S_; ++j) acc += wrow[j] * vbase[(size_t)j * B_ * E_ + l];
    ap[w][l] = acc;
    __syncthreads();

    const float* wo = Wout + l * E_;
    const float* apw = ap[w];
    float oacc = bout[l];
    #pragma unroll 4
    for (int e = 0; e < E_; ++e) oacc += apw[e] * wo[e];
    out[((size_t)i * B_ + b) * E_ + l] = oacc;
}

// ---------------------------------------------------------------------------
extern "C" void kernel_launch(void* const* d_in, const int* in_sizes, int n_in,
                              void* d_out, int out_size, void* d_ws, size_t ws_size,
                              hipStream_t stream)
{
    const float* qin = (const float*)d_in[0];
    const float* kin = (const float*)d_in[1];
    const float* vin = (const float*)d_in[2];
    const float* rel = (const float*)d_in[3];
    const float* ipw = (const float*)d_in[4];
    const float* ipb = (const float*)d_in[5];
    const float* rw  = (const float*)d_in[6];
    const float* rb  = (const float*)d_in[7];
    const float* ow  = (const float*)d_in[8];
    const float* obias = (const float*)d_in[9];

    float* qkv = (float*)d_ws;                        // 3*64*128*64 fl = 6 MB
    float* logits = qkv + 3 * T_ * B_ * E_;           // [i][b][h][j]  = 8 MB
    ushort* wBf  = (ushort*)(logits + (size_t)T_ * S_ * B_ * H_); // 20 KB (+pad)
    ushort* kpbF = wBf + 16384;                       // 64 pages x 16 KB = 1 MB

    float* out = (float*)d_out;

    k_qkv<<<dim3(257), dim3(256), 0, stream>>>(qin, kin, vin, ipw, ipb, qkv,
                                               rw, rb, wBf, (unsigned int*)kpbF);
    k_logits_mfma<<<dim3(512), dim3(512), 0, stream>>>(rel, wBf, kpbF, rb, qkv, logits);
    k_attn<<<dim3(2048), dim3(256), 0, stream>>>(logits, qkv, ow, obias, out);
}